// Round 1
// 262.007 us; speedup vs baseline: 1.0687x; 1.0687x over previous
//
#include <hip/hip_runtime.h>

#define D 128
#define N_SRC 100000
#define N_DST 100000
#define N_EDGES 640000

#define SCAN_BLK 1024
#define N_SCAN_BLOCKS ((N_DST + SCAN_BLK - 1) / SCAN_BLK)   // 98

#define HIST_BLOCKS ((N_EDGES + 255) / 256)                 // 2500
#define CVT_BLOCKS  ((N_SRC * D / 8) / 256)                 // 6250 (exact)
#define PACKW_BLOCKS 128

typedef __attribute__((ext_vector_type(8))) short s8v;
typedef __attribute__((ext_vector_type(4))) float f32x4;

__device__ __forceinline__ unsigned short f2bf(float f) {
    unsigned int u = __float_as_uint(f);
    u += 0x7fffu + ((u >> 16) & 1u);   // round-to-nearest-even
    return (unsigned short)(u >> 16);
}

__device__ __forceinline__ unsigned int pk2(float a, float b) {
    return (unsigned int)f2bf(a) | ((unsigned int)f2bf(b) << 16);
}

// ---- prep: histogram + h_src->bf16 (into d_out rows [0,64) words) + pack W
// Three disjoint block ranges; whole blocks take one path (no divergence).
__global__ __launch_bounds__(256) void prep(
    const int* __restrict__ dst_idx, int* __restrict__ counts,
    const float* __restrict__ h_src, unsigned int* __restrict__ A32,
    const float* __restrict__ W, unsigned short* __restrict__ Bp)
{
    const int blk = blockIdx.x;
    const int tid = threadIdx.x;
    if (blk < HIST_BLOCKS) {
        int e = blk * 256 + tid;
        if (e < N_EDGES) atomicAdd(&counts[dst_idx[e]], 1);
    } else if (blk < HIST_BLOCKS + CVT_BLOCKS) {
        // convert 8 f32 -> 8 bf16 per thread; dest = first 256 B of d_out row r
        int id = (blk - HIST_BLOCKS) * 256 + tid;      // [0, 1.6e6)
        size_t e = (size_t)id * 8;
        const float4* p = (const float4*)(h_src + e);
        float4 x = p[0], y = p[1];
        uint4 o;
        o.x = pk2(x.x, x.y); o.y = pk2(x.z, x.w);
        o.z = pk2(y.x, y.y); o.w = pk2(y.z, y.w);
        int r = id >> 4;            // 16 threads per 128-elem row
        int c = (id & 15) * 8;      // element offset within row
        *(uint4*)(A32 + (size_t)r * 128 + (c >> 1)) = o;
    } else {
        // pack W into MFMA B-fragment order (bf16)
        int id = (blk - HIST_BLOCKS - CVT_BLOCKS) * 256 + tid;
        if (id < 32768) {
            int j = id & 7;
            int l = (id >> 3) & 63;
            int t = (id >> 9) & 7;
            int s = id >> 12;
            int k = s * 32 + (l >> 4) * 8 + j;
            int n = t * 16 + (l & 15);
            Bp[id] = f2bf(W[k * D + n]);
        }
    }
}

// ---- CSR build ----------------------------------------------------------

__global__ __launch_bounds__(256) void scan_blocks(
    const int* __restrict__ counts, int* __restrict__ row_start,
    int* __restrict__ block_sums)
{
    __shared__ int sh[256];
    const int tid = threadIdx.x;
    const int base = blockIdx.x * SCAN_BLK + tid * 4;
    int v[4];
    int local = 0;
#pragma unroll
    for (int k = 0; k < 4; k++) {
        int idx = base + k;
        v[k] = (idx < N_DST) ? counts[idx] : 0;
        local += v[k];
    }
    sh[tid] = local;
    __syncthreads();
    for (int off = 1; off < 256; off <<= 1) {
        int t = (tid >= off) ? sh[tid - off] : 0;
        __syncthreads();
        sh[tid] += t;
        __syncthreads();
    }
    int run = (tid == 0) ? 0 : sh[tid - 1];
    if (tid == 255) block_sums[blockIdx.x] = sh[255];
#pragma unroll
    for (int k = 0; k < 4; k++) {
        int idx = base + k;
        if (idx < N_DST) row_start[idx] = run;
        run += v[k];
    }
}

// top-level scan of the 98 block sums is redundantly done per block in LDS
// (98 ints, L2-hot) — saves a separate scan_top launch.
__global__ __launch_bounds__(256) void add_offsets(
    int* __restrict__ row_start, const int* __restrict__ block_sums,
    int* __restrict__ cursor)
{
    __shared__ int sh[128];
    const int tid = threadIdx.x;
    if (tid < 128) sh[tid] = (tid < N_SCAN_BLOCKS) ? block_sums[tid] : 0;
    __syncthreads();
    for (int off = 1; off < 128; off <<= 1) {
        int t = (tid < 128 && tid >= off) ? sh[tid - off] : 0;
        __syncthreads();
        if (tid < 128) sh[tid] += t;
        __syncthreads();
    }
    int i = blockIdx.x * 256 + tid;
    if (i < N_DST) {
        int blk = i / SCAN_BLK;
        int off = (blk == 0) ? 0 : sh[blk - 1];
        int v = row_start[i] + off;
        row_start[i] = v;
        cursor[i] = v;
    }
    if (i == 0) row_start[N_DST] = N_EDGES;
}

__global__ __launch_bounds__(256) void scatter_perm(
    const int* __restrict__ src_idx, const int* __restrict__ dst_idx,
    int* __restrict__ cursor, int* __restrict__ edge_src)
{
    int e = blockIdx.x * 256 + threadIdx.x;
    if (e < N_EDGES) {
        int d = dst_idx[e];
        int pos = atomicAdd(&cursor[d], 1);
        edge_src[pos] = src_idx[e];
    }
}

// ---- Aggregation: TWO destination rows per wave (one per 32-lane half) --
// Gathers the pre-converted bf16 rows (256 B each) instead of 512-B f32
// rows: halves the gathered bytes and (at 8B/lane x 8-deep batch) doubles
// the independent rows in flight per wave. Accumulates in f32.
__global__ __launch_bounds__(256) void aggregate(
    const unsigned short* __restrict__ hs16,   // d_out as u16: row r at r*256, elems [0,128)
    const int* __restrict__ row_start,
    const int* __restrict__ edge_src, unsigned int* __restrict__ A32)
{
    const int wave = threadIdx.x >> 6;
    const int half = (threadIdx.x >> 5) & 1;
    const int hl = threadIdx.x & 31;
    const int row = blockIdx.x * 8 + wave * 2 + half;
    const int start = row_start[row];
    const int deg = row_start[row + 1] - start;
    f32x4 acc = {0.f, 0.f, 0.f, 0.f};
    for (int base = 0; base < deg; base += 8) {
        // lanes hl&7 of each half hold the batch's (clamped) edge ids
        int j = base + (hl & 7);
        int myid = edge_src[start + min(j, deg - 1)];
#pragma unroll
        for (int t = 0; t < 8; t++) {
            int s = __shfl(myid, t, 32);   // broadcast within this half-wave
            uint2 u = *(const uint2*)(hs16 + (size_t)s * 256 + hl * 4);
            float m = ((base + t) < deg) ? 1.f : 0.f;
            acc.x = fmaf(__uint_as_float(u.x << 16), m, acc.x);
            acc.y = fmaf(__uint_as_float(u.x & 0xffff0000u), m, acc.y);
            acc.z = fmaf(__uint_as_float(u.y << 16), m, acc.z);
            acc.w = fmaf(__uint_as_float(u.y & 0xffff0000u), m, acc.w);
        }
    }
    const float inv = 1.0f / fmaxf((float)deg, 1.0f);
    uint2 o;
    o.x = pk2(acc.x * inv, acc.y * inv);
    o.y = pk2(acc.z * inv, acc.w * inv);
    *(uint2*)(A32 + (size_t)row * 128 + 64 + hl * 2) = o;
}

// ---- Projection via MFMA 16x16x32 bf16, 32 rows per wave ----------------
__global__ __launch_bounds__(256, 4) void mfma_gemm(
    const float* __restrict__ h_dst,
    const unsigned short* __restrict__ A,   // d_out viewed as u16[N_DST][256]
    const unsigned short* __restrict__ Bp,  // packed W fragments (64 KB)
    const float* __restrict__ bias,
    float* __restrict__ out)
{
    const int wave = threadIdx.x >> 6;
    const int lane = threadIdx.x & 63;
    const int row0 = (blockIdx.x * 4 + wave) * 32;
    if (row0 >= N_DST) return;
    const int quad = lane >> 4;
    const int lr = lane & 15;
    const int r0 = row0 + lr;
    const int r1 = row0 + 16 + lr;

    f32x4 acc0[8], acc1[8];
#pragma unroll
    for (int t = 0; t < 8; t++) {
        acc0[t] = (f32x4){0.f, 0.f, 0.f, 0.f};
        acc1[t] = (f32x4){0.f, 0.f, 0.f, 0.f};
    }

    const float* p0 = h_dst + (size_t)r0 * D + quad * 8;
    const float* p1 = h_dst + (size_t)r1 * D + quad * 8;
    const unsigned short* q0 = A + (size_t)r0 * 256 + 128 + quad * 8;
    const unsigned short* q1 = A + (size_t)r1 * 256 + 128 + quad * 8;

    // K = 0..127: h_dst, convert f32 -> bf16 fragments in-register.
#pragma unroll
    for (int s = 0; s < 4; s++) {
        float4 x0 = *(const float4*)(p0 + s * 32);
        float4 y0 = *(const float4*)(p0 + s * 32 + 4);
        float4 x1 = *(const float4*)(p1 + s * 32);
        float4 y1 = *(const float4*)(p1 + s * 32 + 4);
        unsigned short a0u[8], a1u[8];
        a0u[0]=f2bf(x0.x); a0u[1]=f2bf(x0.y); a0u[2]=f2bf(x0.z); a0u[3]=f2bf(x0.w);
        a0u[4]=f2bf(y0.x); a0u[5]=f2bf(y0.y); a0u[6]=f2bf(y0.z); a0u[7]=f2bf(y0.w);
        a1u[0]=f2bf(x1.x); a1u[1]=f2bf(x1.y); a1u[2]=f2bf(x1.z); a1u[3]=f2bf(x1.w);
        a1u[4]=f2bf(y1.x); a1u[5]=f2bf(y1.y); a1u[6]=f2bf(y1.z); a1u[7]=f2bf(y1.w);
        s8v a0 = *(s8v*)a0u;
        s8v a1 = *(s8v*)a1u;
#pragma unroll
        for (int t = 0; t < 8; t++) {
            s8v bf = *(const s8v*)(Bp + ((size_t)(s * 8 + t) * 64 + lane) * 8);
            acc0[t] = __builtin_amdgcn_mfma_f32_16x16x32_bf16(a0, bf, acc0[t], 0, 0, 0);
            acc1[t] = __builtin_amdgcn_mfma_f32_16x16x32_bf16(a1, bf, acc1[t], 0, 0, 0);
        }
    }
    // K = 128..255: bf16 h_N straight from d_out.
#pragma unroll
    for (int s = 4; s < 8; s++) {
        s8v a0 = *(const s8v*)(q0 + (s - 4) * 32);
        s8v a1 = *(const s8v*)(q1 + (s - 4) * 32);
#pragma unroll
        for (int t = 0; t < 8; t++) {
            s8v bf = *(const s8v*)(Bp + ((size_t)(s * 8 + t) * 64 + lane) * 8);
            acc0[t] = __builtin_amdgcn_mfma_f32_16x16x32_bf16(a0, bf, acc0[t], 0, 0, 0);
            acc1[t] = __builtin_amdgcn_mfma_f32_16x16x32_bf16(a1, bf, acc1[t], 0, 0, 0);
        }
    }

#pragma unroll
    for (int t = 0; t < 8; t++) {
        float bv = bias[t * 16 + lr];
#pragma unroll
        for (int r = 0; r < 4; r++) {
            int rowa = row0 + quad * 4 + r;
            int rowb = row0 + 16 + quad * 4 + r;
            out[(size_t)rowa * D + t * 16 + lr] = acc0[t][r] + bv;
            out[(size_t)rowb * D + t * 16 + lr] = acc1[t][r] + bv;
        }
    }
}

extern "C" void kernel_launch(void* const* d_in, const int* in_sizes, int n_in,
                              void* d_out, int out_size, void* d_ws, size_t ws_size,
                              hipStream_t stream) {
    const float* h_src  = (const float*)d_in[0];
    const float* h_dst  = (const float*)d_in[1];
    const int* src_idx  = (const int*)d_in[2];
    const int* dst_idx  = (const int*)d_in[3];
    const float* W      = (const float*)d_in[4];
    const float* b      = (const float*)d_in[5];
    float* out = (float*)d_out;

    // Workspace: Bp first (16B-aligned), then CSR int arrays (~3.9 MB total)
    unsigned short* Bp = (unsigned short*)d_ws;         // 32768 u16 = 64 KB
    int* ws_i          = (int*)((char*)d_ws + 65536);
    int* row_start     = ws_i;                          // N_DST+1
    int* cursor        = row_start + (N_DST + 1);       // N_DST
    int* counts        = cursor + N_DST;                // N_DST
    int* block_sums    = counts + N_DST;                // N_SCAN_BLOCKS
    int* edge_src      = block_sums + N_SCAN_BLOCKS;    // N_EDGES

    hipMemsetAsync(counts, 0, (size_t)N_DST * sizeof(int), stream);

    // hist + h_src->bf16 (into d_out first halves) + pack_W, one launch
    prep<<<HIST_BLOCKS + CVT_BLOCKS + PACKW_BLOCKS, 256, 0, stream>>>(
        dst_idx, counts, h_src, (unsigned int*)d_out, W, Bp);

    scan_blocks<<<N_SCAN_BLOCKS, 256, 0, stream>>>(counts, row_start, block_sums);
    add_offsets<<<(N_DST + 255) / 256, 256, 0, stream>>>(row_start, block_sums, cursor);
    scatter_perm<<<(N_EDGES + 255) / 256, 256, 0, stream>>>(src_idx, dst_idx, cursor, edge_src);

    aggregate<<<N_DST / 8, 256, 0, stream>>>(
        (const unsigned short*)d_out, row_start, edge_src, (unsigned int*)d_out);

    int gemm_blocks = (N_DST / 32 + 3) / 4;   // 3125 waves -> 782 blocks
    mfma_gemm<<<gemm_blocks, 256, 0, stream>>>(
        h_dst, (const unsigned short*)d_out, Bp, b, out);
}